// Round 5
// baseline (252.917 us; speedup 1.0000x reference)
//
#include <hip/hip_runtime.h>

#define HDIM 256
#define TDIM 256
#define VOUT 10
#define BC   8     // batch rows per block -> 256 blocks, every CU busy

typedef _Float16 f16x8 __attribute__((ext_vector_type(8)));
typedef float    f32x4 __attribute__((ext_vector_type(4)));

__device__ __forceinline__ float fast_tanh(float a) {
    // tanh(a) = 1 - 2/(exp(2a)+1). |a| bounded (~10) -> no clamp needed.
    float e = __expf(2.0f * a);
    return 1.0f - 2.0f * __builtin_amdgcn_rcpf(e + 1.0f);
}

// Swapped-operand MFMA recurrence, BC=8: per step D = Wh^T (256x256) x v^T (256x8).
// MFMA N=16 slots; lanes with n>=8 alias batch row n&7 (same-address LDS broadcast,
// bitwise-duplicate results, writes predicated to n<8).
// Wave w (0..7) owns h-cols [32w, 32w+32) = 2 M-tiles. Lane l: n = l&15, g = l>>4.
// D layout (m89): hcol = 32w+16mt+4g+rg, batch col = n.
// v in LDS as [rn][hcol] f16, 16B chunks XOR-swizzled: chunk' = chunk ^ rn.
__global__ __launch_bounds__(512, 2) void rnn_fwd_mfma_b8(
    const float* __restrict__ x,    // [B, T]
    const float* __restrict__ We,   // [H]
    const float* __restrict__ be,   // [H]
    const float* __restrict__ Wh,   // [H, H] (in, out)
    const float* __restrict__ bh,   // [H]
    const float* __restrict__ Wo,   // [H, V]
    const float* __restrict__ bo,   // [V]
    float* __restrict__ out)        // [B, V]
{
    __shared__ __align__(16) char vraw[2][BC * HDIM * 2];  // 2 x 4 KB f16, swizzled
    __shared__ float x_lds[BC][TDIM + 2];                  // stride 258
    __shared__ float h_fin[BC][HDIM + 1];

    const int tid = threadIdx.x;
    const int l   = tid & 63;
    const int w   = tid >> 6;       // wave id 0..7 -> h-cols [32w, 32w+32)
    const int n   = l & 15;         // MFMA N slot
    const int rn  = n & 7;          // actual batch row (n>=8 aliases)
    const int g   = l >> 4;         // lane group
    const int r0  = blockIdx.x * BC;

    // ---- stage x (coalesced) ----
    for (int k = tid; k < BC * TDIM; k += 512) {
        int r = k >> 8, t = k & 255;
        x_lds[r][t] = x[(r0 + r) * TDIM + t];
    }

    // ---- W_h -> register fragments (one-time) ----
    // wfrag[mt][kt][e] = Wh^T[32w+16mt+n][kt*32+g*8+e] = Wh[kt*32+g*8+e][32w+16mt+n]
    f16x8 wfrag[2][8];
    #pragma unroll
    for (int mt = 0; mt < 2; ++mt) {
        const int col = 32 * w + 16 * mt + n;   // full n: A-frag row
        #pragma unroll
        for (int kt = 0; kt < 8; ++kt) {
            #pragma unroll
            for (int e = 0; e < 8; ++e)
                wfrag[mt][kt][e] = (_Float16)Wh[(kt * 32 + g * 8 + e) * HDIM + col];
        }
    }

    // ---- per-lane We/be/bh for owned hcols (hcol = 32w + 16mt + 4g + rg) ----
    float Wef[2][4], bef[2][4], bhf[2][4];
    #pragma unroll
    for (int mt = 0; mt < 2; ++mt) {
        const int hc = 32 * w + 16 * mt + 4 * g;
        #pragma unroll
        for (int rg = 0; rg < 4; ++rg) {
            Wef[mt][rg] = We[hc + rg];
            bef[mt][rg] = be[hc + rg];
            bhf[mt][rg] = bh[hc + rg];
        }
    }

    // ---- swizzled LDS byte addresses (16B chunk' = chunk ^ rn) ----
    // read kt: v[rn][kt*32 + g*8 ..] -> chunk 4kt+g
    const int base_r = rn * 512 + ((g ^ (rn & 3)) << 4);
    const int kthi   = rn >> 2;
    // write mt: 4 f16 at hcol0 = 32w+16mt+4g -> chunk 4w+2mt+(g>>1), half 8*(g&1)
    int addr_w[2];
    #pragma unroll
    for (int mt = 0; mt < 2; ++mt)
        addr_w[mt] = rn * 512 + (((4 * w + 2 * mt + (g >> 1)) ^ rn) << 4) + 8 * (g & 1);

    const bool writer = (n < 8);

    __syncthreads();

    // ---- v(0) = tanh(x[:,0]*We + be)  (h0 = 0) ----
    {
        const float xv = x_lds[rn][0];
        #pragma unroll
        for (int mt = 0; mt < 2; ++mt) {
            union { _Float16 h[4]; uint2 u2; } pk;
            #pragma unroll
            for (int rg = 0; rg < 4; ++rg)
                pk.h[rg] = (_Float16)fast_tanh(xv * Wef[mt][rg] + bef[mt][rg]);
            if (writer) *(uint2*)(&vraw[0][0] + addr_w[mt]) = pk.u2;
        }
    }
    __syncthreads();

    int cur = 0;
    #pragma unroll 1
    for (int t = 0; t < TDIM; ++t) {
        const char* vr = &vraw[cur][0];
        const bool last = (t + 1 == TDIM);

        // LDS reads first (lgkm in flight); 16-lane phases hit all 32 banks
        // exactly once (8 unique chunks x 2-lane broadcast)
        f16x8 bfrag[8];
        #pragma unroll
        for (int kt = 0; kt < 8; ++kt)
            bfrag[kt] = *(const f16x8*)(vr + base_r + ((kt ^ kthi) << 6));

        // independent inp-tanh fills the wait shadow
        float inpv[2][4];
        if (!last) {
            const float xv = x_lds[rn][t + 1];
            #pragma unroll
            for (int mt = 0; mt < 2; ++mt)
                #pragma unroll
                for (int rg = 0; rg < 4; ++rg)
                    inpv[mt][rg] = fast_tanh(xv * Wef[mt][rg] + bef[mt][rg]);
        }

        // 4 independent MFMA chains (mt x kt-parity), 4-deep each
        f32x4 accE[2], accO[2];
        #pragma unroll
        for (int mt = 0; mt < 2; ++mt) {
            accE[mt][0] = bhf[mt][0]; accE[mt][1] = bhf[mt][1];
            accE[mt][2] = bhf[mt][2]; accE[mt][3] = bhf[mt][3];
            accO[mt][0] = 0.0f; accO[mt][1] = 0.0f;
            accO[mt][2] = 0.0f; accO[mt][3] = 0.0f;
        }
        #pragma unroll
        for (int kp = 0; kp < 4; ++kp) {
            #pragma unroll
            for (int mt = 0; mt < 2; ++mt)
                accE[mt] = __builtin_amdgcn_mfma_f32_16x16x32_f16(
                    wfrag[mt][2 * kp], bfrag[2 * kp], accE[mt], 0, 0, 0);
            #pragma unroll
            for (int mt = 0; mt < 2; ++mt)
                accO[mt] = __builtin_amdgcn_mfma_f32_16x16x32_f16(
                    wfrag[mt][2 * kp + 1], bfrag[2 * kp + 1], accO[mt], 0, 0, 0);
        }

        if (!last) {
            char* vw = &vraw[cur ^ 1][0];
            #pragma unroll
            for (int mt = 0; mt < 2; ++mt) {
                union { _Float16 h[4]; uint2 u2; } pk;
                #pragma unroll
                for (int rg = 0; rg < 4; ++rg)
                    pk.h[rg] = (_Float16)(fast_tanh(accE[mt][rg] + accO[mt][rg])
                                          + inpv[mt][rg]);
                if (writer) *(uint2*)(vw + addr_w[mt]) = pk.u2;
            }
        } else {
            #pragma unroll
            for (int mt = 0; mt < 2; ++mt) {
                const int hc = 32 * w + 16 * mt + 4 * g;
                #pragma unroll
                for (int rg = 0; rg < 4; ++rg)
                    if (writer) h_fin[rn][hc + rg] = fast_tanh(accE[mt][rg] + accO[mt][rg]);
            }
        }
        cur ^= 1;
        __syncthreads();
    }

    // ---- epilogue: out[r][v] = bo[v] + sum_i h[r][i] * Wo[i*V+v] ----
    if (tid < BC * VOUT) {
        const int r = tid / VOUT, vc = tid - r * VOUT;
        float sacc = bo[vc];
        #pragma unroll 8
        for (int i = 0; i < HDIM; ++i)
            sacc = fmaf(h_fin[r][i], Wo[i * VOUT + vc], sacc);
        out[(r0 + r) * VOUT + vc] = sacc;
    }
}

extern "C" void kernel_launch(void* const* d_in, const int* in_sizes, int n_in,
                              void* d_out, int out_size, void* d_ws, size_t ws_size,
                              hipStream_t stream) {
    const float* x  = (const float*)d_in[0];
    const float* We = (const float*)d_in[1];
    const float* be = (const float*)d_in[2];
    const float* Wh = (const float*)d_in[3];
    const float* bh = (const float*)d_in[4];
    const float* Wo = (const float*)d_in[5];
    const float* bo = (const float*)d_in[6];
    float* out = (float*)d_out;

    const int B = in_sizes[0] / TDIM;      // 2048
    const int nblocks = B / BC;            // 256

    rnn_fwd_mfma_b8<<<nblocks, 512, 0, stream>>>(x, We, be, Wh, bh, Wo, bo, out);
}

// Round 6
// 178.932 us; speedup vs baseline: 1.4135x; 1.4135x over previous
//
#include <hip/hip_runtime.h>

#define HDIM 256
#define TDIM 256
#define VOUT 10
#define BC   8     // batch rows per block -> 256 blocks, every CU busy

typedef _Float16 f16x8 __attribute__((ext_vector_type(8)));
typedef _Float16 f16x2 __attribute__((ext_vector_type(2)));
typedef float    f32x4 __attribute__((ext_vector_type(4)));

__device__ __forceinline__ float fast_tanh(float a) {
    // tanh(a) = 1 - 2/(exp(2a)+1). |a| bounded (~32) -> no clamp needed.
    float e = __expf(2.0f * a);
    return 1.0f - 2.0f * __builtin_amdgcn_rcpf(e + 1.0f);
}

// Swapped-operand MFMA recurrence, BC=8. Per step D = Wh^T (256x256) x v^T (256x8).
// MFMA N=16 slots; lanes n>=8 alias batch row rn=n&7 (same-address broadcast reads).
// Wave w owns h-cols [32w,32w+32) (2 M-tiles). D layout: hcol=32w+16mt+4g+rg, col=n.
// v LDS layout: 16B chunk (c=hcol>>3, rn): addr = c*128 + rn*16  (conflict-free:
//   each 8-lane read phase = one 128B line; split-rg b32 writes hit 32 banks once).
// inp (embedding tanh) = rolling 4-plane f32 buffer, plane tq filled cooperatively
//   at iteration tq-3 (512 thr x 4 unique vals) -> no duplicate transcendentals.
__global__ __launch_bounds__(512, 2) void rnn_fwd_v6(
    const float* __restrict__ x,    // [B, T]
    const float* __restrict__ We,   // [H]
    const float* __restrict__ be,   // [H]
    const float* __restrict__ Wh,   // [H, H] (in, out)
    const float* __restrict__ bh,   // [H]
    const float* __restrict__ Wo,   // [H, V]
    const float* __restrict__ bo,   // [V]
    float* __restrict__ out)        // [B, V]
{
    __shared__ __align__(16) char  vraw[2][BC * HDIM * 2];   // 2 x 4 KB f16
    __shared__ __align__(16) float inp_lds[4][BC * HDIM];    // 4 x 8 KB f32 planes
    __shared__ float x_lds[BC][TDIM + 2];                    // stride 258
    __shared__ float h_fin[BC][HDIM + 1];

    const int tid = threadIdx.x;
    const int l   = tid & 63;
    const int w   = tid >> 6;       // wave 0..7 -> h-cols [32w, 32w+32)
    const int n   = l & 15;         // MFMA N slot
    const int rn  = n & 7;          // batch row
    const int hi  = n >> 3;         // rg-pair selector (dedup split)
    const int g   = l >> 4;
    const int r0  = blockIdx.x * BC;

    // ---- stage x (coalesced) ----
    for (int k = tid; k < BC * TDIM; k += 512) {
        int r = k >> 8, t = k & 255;
        x_lds[r][t] = x[(r0 + r) * TDIM + t];
    }

    // ---- W_h -> register fragments ----
    // wfrag[mt][kt][e] = Wh[(kt*32+g*8+e)*H + 32w+16mt+n]
    f16x8 wfrag[2][8];
    #pragma unroll
    for (int mt = 0; mt < 2; ++mt) {
        const int col = 32 * w + 16 * mt + n;
        #pragma unroll
        for (int kt = 0; kt < 8; ++kt) {
            #pragma unroll
            for (int e = 0; e < 8; ++e)
                wfrag[mt][kt][e] = (_Float16)Wh[(kt * 32 + g * 8 + e) * HDIM + col];
        }
    }

    // bh for acc init (hcol = 32w+16mt+4g+rg)
    float bhf[2][4];
    #pragma unroll
    for (int mt = 0; mt < 2; ++mt)
        #pragma unroll
        for (int rg = 0; rg < 4; ++rg)
            bhf[mt][rg] = bh[32 * w + 16 * mt + 4 * g + rg];

    // ---- burst (inp-plane) assignment: thread -> (chunk c_b, row rn_b, half hf_b) ----
    const int c_b  = tid >> 4;          // 0..31 (8 hcols each)
    const int rn_b = (tid >> 1) & 7;
    const int hf_b = tid & 1;           // low/high 4 hcols of the chunk
    float Web[4], beb[4];
    #pragma unroll
    for (int r = 0; r < 4; ++r) {
        Web[r] = We[c_b * 8 + hf_b * 4 + r];
        beb[r] = be[c_b * 8 + hf_b * 4 + r];
    }
    const int bidx = c_b * 64 + rn_b * 8 + hf_b * 4;   // float index in a plane

    // ---- main-loop LDS addresses (bytes) ----
    const int base_r = g * 128 + rn * 16;              // bfrag: + kt*512
    int addr_w[2];                                     // v write/copy (b32, 2 f16)
    #pragma unroll
    for (int mt = 0; mt < 2; ++mt)
        addr_w[mt] = (4 * w + 2 * mt + (g >> 1)) * 128 + rn * 16 + (g & 1) * 8 + hi * 4;
    int iidx[2];                                       // inp read (2 f32)
    #pragma unroll
    for (int mt = 0; mt < 2; ++mt)
        iidx[mt] = (4 * w + 2 * mt + (g >> 1)) * 64 + rn * 8 + (g & 1) * 4 + hi * 2;

    __syncthreads();

    // ---- prologue: inp planes tq = 0,1,2 ----
    #pragma unroll
    for (int tq = 0; tq < 3; ++tq) {
        const float xv = x_lds[rn_b][tq];
        f32x4 pk;
        #pragma unroll
        for (int r = 0; r < 4; ++r)
            pk[r] = fast_tanh(xv * Web[r] + beb[r]);
        *(f32x4*)&inp_lds[tq][bidx] = pk;
    }
    __syncthreads();

    // ---- v(0) = inp(0): copy plane 0 -> vraw[0] (f32 -> f16) ----
    #pragma unroll
    for (int mt = 0; mt < 2; ++mt) {
        const float v0 = inp_lds[0][iidx[mt] + 0];
        const float v1 = inp_lds[0][iidx[mt] + 1];
        f16x2 pk; pk[0] = (_Float16)v0; pk[1] = (_Float16)v1;
        *(f16x2*)(&vraw[0][0] + addr_w[mt]) = pk;
    }
    __syncthreads();

    int cur = 0;
    #pragma unroll 1
    for (int t = 0; t < TDIM; ++t) {
        const char* vr = &vraw[cur][0];
        const bool last = (t + 1 == TDIM);

        // B-frags: 8-lane phases each cover one 128B line (conflict-free)
        f16x8 bfrag[8];
        #pragma unroll
        for (int kt = 0; kt < 8; ++kt)
            bfrag[kt] = *(const f16x8*)(vr + base_r + kt * 512);

        // inp(t+1) pair for this step's v-write
        float ip[2][2];
        {
            const float* ipl = &inp_lds[(t + 1) & 3][0];
            #pragma unroll
            for (int mt = 0; mt < 2; ++mt) {
                ip[mt][0] = ipl[iidx[mt] + 0];
                ip[mt][1] = ipl[iidx[mt] + 1];
            }
        }

        // shadow: cooperative inp plane tq = t+3 (unique work, hides under MFMA)
        {
            const int tq = t + 3;
            if (tq < TDIM) {
                const float xv = x_lds[rn_b][tq];
                f32x4 pk;
                #pragma unroll
                for (int r = 0; r < 4; ++r)
                    pk[r] = fast_tanh(xv * Web[r] + beb[r]);
                *(f32x4*)&inp_lds[tq & 3][bidx] = pk;
            }
        }

        // 4 independent MFMA chains (mt x kt-parity), 4-deep
        f32x4 accE[2], accO[2];
        #pragma unroll
        for (int mt = 0; mt < 2; ++mt) {
            accE[mt][0] = bhf[mt][0]; accE[mt][1] = bhf[mt][1];
            accE[mt][2] = bhf[mt][2]; accE[mt][3] = bhf[mt][3];
            accO[mt][0] = 0.0f; accO[mt][1] = 0.0f;
            accO[mt][2] = 0.0f; accO[mt][3] = 0.0f;
        }
        #pragma unroll
        for (int kp = 0; kp < 4; ++kp) {
            #pragma unroll
            for (int mt = 0; mt < 2; ++mt)
                accE[mt] = __builtin_amdgcn_mfma_f32_16x16x32_f16(
                    wfrag[mt][2 * kp], bfrag[2 * kp], accE[mt], 0, 0, 0);
            #pragma unroll
            for (int mt = 0; mt < 2; ++mt)
                accO[mt] = __builtin_amdgcn_mfma_f32_16x16x32_f16(
                    wfrag[mt][2 * kp + 1], bfrag[2 * kp + 1], accO[mt], 0, 0, 0);
        }

        // dedup'd epilogue: lane handles rg-pair {2hi, 2hi+1} only
        if (!last) {
            char* vw = &vraw[cur ^ 1][0];
            #pragma unroll
            for (int mt = 0; mt < 2; ++mt) {
                const float a0 = hi ? (accE[mt][2] + accO[mt][2]) : (accE[mt][0] + accO[mt][0]);
                const float a1 = hi ? (accE[mt][3] + accO[mt][3]) : (accE[mt][1] + accO[mt][1]);
                const float s0 = fast_tanh(a0) + ip[mt][0];
                const float s1 = fast_tanh(a1) + ip[mt][1];
                f16x2 pk; pk[0] = (_Float16)s0; pk[1] = (_Float16)s1;
                *(f16x2*)(vw + addr_w[mt]) = pk;
            }
        } else {
            #pragma unroll
            for (int mt = 0; mt < 2; ++mt) {
                const float a0 = hi ? (accE[mt][2] + accO[mt][2]) : (accE[mt][0] + accO[mt][0]);
                const float a1 = hi ? (accE[mt][3] + accO[mt][3]) : (accE[mt][1] + accO[mt][1]);
                const int hc = 32 * w + 16 * mt + 4 * g + 2 * hi;
                h_fin[rn][hc + 0] = fast_tanh(a0);
                h_fin[rn][hc + 1] = fast_tanh(a1);
            }
        }
        cur ^= 1;
        __syncthreads();
    }

    // ---- epilogue: out[r][v] = bo[v] + sum_i h[r][i] * Wo[i*V+v] ----
    if (tid < BC * VOUT) {
        const int r = tid / VOUT, vc = tid - r * VOUT;
        float sacc = bo[vc];
        #pragma unroll 8
        for (int i = 0; i < HDIM; ++i)
            sacc = fmaf(h_fin[r][i], Wo[i * VOUT + vc], sacc);
        out[(r0 + r) * VOUT + vc] = sacc;
    }
}

extern "C" void kernel_launch(void* const* d_in, const int* in_sizes, int n_in,
                              void* d_out, int out_size, void* d_ws, size_t ws_size,
                              hipStream_t stream) {
    const float* x  = (const float*)d_in[0];
    const float* We = (const float*)d_in[1];
    const float* be = (const float*)d_in[2];
    const float* Wh = (const float*)d_in[3];
    const float* bh = (const float*)d_in[4];
    const float* Wo = (const float*)d_in[5];
    const float* bo = (const float*)d_in[6];
    float* out = (float*)d_out;

    const int B = in_sizes[0] / TDIM;      // 2048
    const int nblocks = B / BC;            // 256

    rnn_fwd_v6<<<nblocks, 512, 0, stream>>>(x, We, be, Wh, bh, Wo, bo, out);
}